// Round 1
// baseline (382.113 us; speedup 1.0000x reference)
//
#include <hip/hip_runtime.h>
#include <hip/hip_bf16.h>

// ZoomAttention: x[2,2048,1024] -> qkv proj -> 16-head attn with -gamma*dist bias -> proj
// All GEMMs as C = A * B^T with bf16 MFMA 16x16x32, f32 accumulate.

typedef __attribute__((ext_vector_type(8))) short bf16x8;
typedef __attribute__((ext_vector_type(4))) float f32x4;
typedef __attribute__((ext_vector_type(4))) unsigned short us4;

#define MFMA(a, b, c) __builtin_amdgcn_mfma_f32_16x16x32_bf16((a), (b), (c), 0, 0, 0)

__device__ __forceinline__ unsigned short f2bf(float f) {
  unsigned u = __float_as_uint(f);
  u += 0x7fffu + ((u >> 16) & 1u);       // round-to-nearest-even
  return (unsigned short)(u >> 16);
}

// ---------- elementwise f32 -> bf16, 8 elems/thread ----------
__global__ __launch_bounds__(256) void k_conv(const float* __restrict__ in,
                                              short* __restrict__ out, int n8) {
  int i = blockIdx.x * blockDim.x + threadIdx.x;
  if (i >= n8) return;
  float4 a = ((const float4*)in)[2 * i];
  float4 b = ((const float4*)in)[2 * i + 1];
  us4 lo, hi;
  lo.x = f2bf(a.x); lo.y = f2bf(a.y); lo.z = f2bf(a.z); lo.w = f2bf(a.w);
  hi.x = f2bf(b.x); hi.y = f2bf(b.y); hi.z = f2bf(b.z); hi.w = f2bf(b.w);
  us4* o = (us4*)(out + 8 * (size_t)i);
  o[0] = lo; o[1] = hi;
}

// ---------- tiled transpose + convert: in[R][C] f32 -> out[C][R] bf16 ----------
__global__ void k_transpose(const float* __restrict__ in, short* __restrict__ out,
                            int R, int C) {
  __shared__ float t[32][33];
  int c0 = blockIdx.x * 32, r0 = blockIdx.y * 32;
  int tx = threadIdx.x, ty = threadIdx.y;
#pragma unroll
  for (int j = 0; j < 32; j += 8)
    t[ty + j][tx] = in[(size_t)(r0 + ty + j) * C + c0 + tx];
  __syncthreads();
#pragma unroll
  for (int j = 0; j < 32; j += 8)
    out[(size_t)(c0 + ty + j) * R + r0 + tx] = (short)f2bf(t[tx][ty + j]);
}

// ---------- GEMM C[M][N] = A[M][K] * (B[N][K])^T, bf16 in, f32 acc ----------
// MODE 0: epilogue scatters qkv columns into Q[bh][n][d], K[bh][n][d], Vt[bh][d][n] (+bias)
// MODE 1: epilogue stores f32 C (+bias) row-major
template <int MODE>
__global__ __launch_bounds__(256) void k_gemm(const short* __restrict__ A,
                                              const short* __restrict__ B,
                                              const float* __restrict__ bias,
                                              void* __restrict__ C0, void* __restrict__ C1,
                                              void* __restrict__ C2, int M, int N, int K) {
  __shared__ __align__(16) short bufA[2][128 * 32];
  __shared__ __align__(16) short bufB[2][128 * 32];
  const int tid = threadIdx.x, lane = tid & 63, wave = tid >> 6;
  const int m0 = blockIdx.y * 128, n0 = blockIdx.x * 128;
  const int wm = (wave >> 1) * 64, wn = (wave & 1) * 64;
  const int KT = K >> 5;
  f32x4 acc[4][4] = {};

  const short* ga = A + (size_t)m0 * K;
  const short* gb = B + (size_t)n0 * K;

#define STAGE(kt, bsel)                                                                   \
  {                                                                                       \
    const short* pa = ga + (kt) * 32;                                                     \
    const short* pb = gb + (kt) * 32;                                                     \
    _Pragma("unroll") for (int i = 0; i < 2; i++) {                                       \
      int s = i * 256 + tid;                                                              \
      __builtin_amdgcn_global_load_lds(                                                   \
          (const __attribute__((address_space(1))) void*)(pa + (size_t)(s >> 2) * K +     \
                                                          (s & 3) * 8),                   \
          (__attribute__((address_space(3))) void*)(&bufA[bsel][(i * 256 + wave * 64) * 8]), \
          16, 0, 0);                                                                      \
      __builtin_amdgcn_global_load_lds(                                                   \
          (const __attribute__((address_space(1))) void*)(pb + (size_t)(s >> 2) * K +     \
                                                          (s & 3) * 8),                   \
          (__attribute__((address_space(3))) void*)(&bufB[bsel][(i * 256 + wave * 64) * 8]), \
          16, 0, 0);                                                                      \
    }                                                                                     \
  }

  STAGE(0, 0)
  for (int kt = 0; kt < KT; ++kt) {
    const int cur = kt & 1;
    __syncthreads();
    if (kt + 1 < KT) STAGE(kt + 1, cur ^ 1)
    bf16x8 af[4], bfr[4];
#pragma unroll
    for (int i = 0; i < 4; i++)
      af[i] = *(const bf16x8*)&bufA[cur][(wm + i * 16 + (lane & 15)) * 32 + (lane >> 4) * 8];
#pragma unroll
    for (int i = 0; i < 4; i++)
      bfr[i] = *(const bf16x8*)&bufB[cur][(wn + i * 16 + (lane & 15)) * 32 + (lane >> 4) * 8];
#pragma unroll
    for (int mi = 0; mi < 4; mi++)
#pragma unroll
      for (int ni = 0; ni < 4; ni++) acc[mi][ni] = MFMA(af[mi], bfr[ni], acc[mi][ni]);
  }
#undef STAGE

#pragma unroll
  for (int mi = 0; mi < 4; mi++)
#pragma unroll
    for (int ni = 0; ni < 4; ni++) {
      int row0 = m0 + wm + mi * 16 + (lane >> 4) * 4;
      int col = n0 + wn + ni * 16 + (lane & 15);
      float bv = bias[col];
      if constexpr (MODE == 0) {
        int which = col >> 10, h = (col >> 6) & 15, d = col & 63;
        int b = row0 >> 11, nt0 = row0 & 2047;
        if (which == 2) {
          us4 pk;
          pk.x = f2bf(acc[mi][ni][0] + bv);
          pk.y = f2bf(acc[mi][ni][1] + bv);
          pk.z = f2bf(acc[mi][ni][2] + bv);
          pk.w = f2bf(acc[mi][ni][3] + bv);
          *(us4*)((short*)C2 + ((size_t)((b << 4) + h) * 64 + d) * 2048 + nt0) = pk;
        } else {
          short* dst = (which == 0) ? (short*)C0 : (short*)C1;
#pragma unroll
          for (int r = 0; r < 4; r++)
            dst[((size_t)((b << 4) + h) * 2048 + nt0 + r) * 64 + d] =
                (short)f2bf(acc[mi][ni][r] + bv);
        }
      } else {
        float* o = (float*)C0;
#pragma unroll
        for (int r = 0; r < 4; r++) o[(size_t)(row0 + r) * N + col] = acc[mi][ni][r] + bv;
      }
    }
}

// ---------- fused attention: per (bh, qblock of 64 rows), flash-style ----------
// Q[bh][n][d], K[bh][n][d], Vt[bh][d][n] bf16; out attn[b*2048+n][h*64+d] bf16
__global__ __launch_bounds__(256) void k_attn(const short* __restrict__ Qb,
                                              const short* __restrict__ Kb,
                                              const short* __restrict__ Vt,
                                              const float* __restrict__ gamma,
                                              const float* __restrict__ dist,
                                              short* __restrict__ attn_out) {
  __shared__ __align__(16) short Plds[4][16][72];
  const int lane = threadIdx.x & 63, wave = threadIdx.x >> 6;
  const int bh = blockIdx.y;
  const int qbase = blockIdx.x * 64 + wave * 16;
  const float g = gamma[bh];
  const float scale = 0.03125f;  // 1024^-0.5
  const size_t head = (size_t)bh * 2048 * 64;

  bf16x8 aq[2];
#pragma unroll
  for (int k0 = 0; k0 < 2; k0++)
    aq[k0] = *(const bf16x8*)&Qb[head + (size_t)(qbase + (lane & 15)) * 64 + k0 * 32 +
                                 (lane >> 4) * 8];

  float m_r[4], l_r[4];
  f32x4 acc[4] = {};
#pragma unroll
  for (int r = 0; r < 4; r++) { m_r[r] = -3.0e38f; l_r[r] = 0.f; }

  for (int kb = 0; kb < 2048; kb += 64) {
    f32x4 s[4] = {};
#pragma unroll
    for (int j = 0; j < 4; j++)
#pragma unroll
      for (int k0 = 0; k0 < 2; k0++) {
        bf16x8 bk = *(const bf16x8*)&Kb[head + (size_t)(kb + j * 16 + (lane & 15)) * 64 +
                                        k0 * 32 + (lane >> 4) * 8];
        s[j] = MFMA(aq[k0], bk, s[j]);
      }
    float pj[4][4];
#pragma unroll
    for (int j = 0; j < 4; j++)
#pragma unroll
      for (int r = 0; r < 4; r++) {
        int qrow = qbase + (lane >> 4) * 4 + r;
        int kcol = kb + j * 16 + (lane & 15);
        pj[j][r] = s[j][r] * scale - g * dist[(size_t)qrow * 2048 + kcol];
      }
#pragma unroll
    for (int r = 0; r < 4; r++) {
      float mx = fmaxf(fmaxf(pj[0][r], pj[1][r]), fmaxf(pj[2][r], pj[3][r]));
#pragma unroll
      for (int off = 1; off < 16; off <<= 1) mx = fmaxf(mx, __shfl_xor(mx, off, 64));
      float mnew = fmaxf(m_r[r], mx);
      float alpha = __expf(m_r[r] - mnew);
      float ps = 0.f;
#pragma unroll
      for (int j = 0; j < 4; j++) {
        pj[j][r] = __expf(pj[j][r] - mnew);
        ps += pj[j][r];
      }
#pragma unroll
      for (int off = 1; off < 16; off <<= 1) ps += __shfl_xor(ps, off, 64);
      l_r[r] = l_r[r] * alpha + ps;
      m_r[r] = mnew;
#pragma unroll
      for (int dj = 0; dj < 4; dj++) acc[dj][r] *= alpha;
    }
    // P -> per-wave LDS (transpose to MFMA A layout); same-wave DS ops are in-order
#pragma unroll
    for (int j = 0; j < 4; j++)
#pragma unroll
      for (int r = 0; r < 4; r++)
        Plds[wave][(lane >> 4) * 4 + r][j * 16 + (lane & 15)] = (short)f2bf(pj[j][r]);
#pragma unroll
    for (int k0 = 0; k0 < 2; k0++) {
      bf16x8 ap = *(const bf16x8*)&Plds[wave][lane & 15][k0 * 32 + (lane >> 4) * 8];
#pragma unroll
      for (int dj = 0; dj < 4; dj++) {
        bf16x8 bv = *(const bf16x8*)&Vt[head + (size_t)(dj * 16 + (lane & 15)) * 2048 + kb +
                                        k0 * 32 + (lane >> 4) * 8];
        acc[dj] = MFMA(ap, bv, acc[dj]);
      }
    }
  }

  const int b = bh >> 4, h = bh & 15;
#pragma unroll
  for (int r = 0; r < 4; r++) {
    float inv = 1.0f / l_r[r];
    int qrow = qbase + (lane >> 4) * 4 + r;
    size_t base = ((size_t)b * 2048 + qrow) * 1024 + h * 64;
#pragma unroll
    for (int dj = 0; dj < 4; dj++)
      attn_out[base + dj * 16 + (lane & 15)] = (short)f2bf(acc[dj][r] * inv);
  }
}

extern "C" void kernel_launch(void* const* d_in, const int* in_sizes, int n_in,
                              void* d_out, int out_size, void* d_ws, size_t ws_size,
                              hipStream_t stream) {
  const float* x = (const float*)d_in[0];       // [2,2048,1024]
  const float* gamma = (const float*)d_in[1];   // [2,16]
  const float* dist = (const float*)d_in[2];    // [2048,2048]
  const float* qkv_w = (const float*)d_in[3];   // [1024,3072]
  const float* qkv_b = (const float*)d_in[4];   // [3072]
  const float* proj_w = (const float*)d_in[5];  // [1024,1024]
  const float* proj_b = (const float*)d_in[6];  // [1024]
  float* out = (float*)d_out;                   // [4096,1024]

  const size_t MB = 1024 * 1024;
  char* ws = (char*)d_ws;
  short* xb = (short*)(ws + 0 * MB);     // 8MB  x bf16 [4096][1024]
  short* wT = (short*)(ws + 8 * MB);     // 6MB  qkv_w^T bf16 [3072][1024]
  short* pT = (short*)(ws + 14 * MB);    // 2MB  proj_w^T bf16 [1024][1024]
  short* Qb = (short*)(ws + 16 * MB);    // 8MB  [32][2048][64]
  short* Kb = (short*)(ws + 24 * MB);    // 8MB
  short* Vt = (short*)(ws + 32 * MB);    // 8MB  [32][64][2048]
  short* attn = (short*)(ws + 0 * MB);   // reuse xb region: [4096][1024] bf16

  // x -> bf16
  k_conv<<<dim3((4096 * 1024 / 8 + 255) / 256), dim3(256), 0, stream>>>(x, xb, 4096 * 1024 / 8);
  // weight transposes
  k_transpose<<<dim3(96, 32), dim3(32, 8), 0, stream>>>(qkv_w, wT, 1024, 3072);
  k_transpose<<<dim3(32, 32), dim3(32, 8), 0, stream>>>(proj_w, pT, 1024, 1024);
  // qkv projection + scatter
  k_gemm<0><<<dim3(24, 32), dim3(256), 0, stream>>>(xb, wT, qkv_b, Qb, Kb, Vt, 4096, 3072, 1024);
  // attention
  k_attn<<<dim3(32, 32), dim3(256), 0, stream>>>(Qb, Kb, Vt, gamma, dist, attn);
  // output projection
  k_gemm<1><<<dim3(8, 32), dim3(256), 0, stream>>>(attn, pT, proj_b, out, nullptr, nullptr,
                                                   4096, 1024, 1024);
}

// Round 2
// 359.455 us; speedup vs baseline: 1.0630x; 1.0630x over previous
//
#include <hip/hip_runtime.h>
#include <hip/hip_bf16.h>

// ZoomAttention: x[2,2048,1024] -> qkv proj -> 16-head attn with -gamma*dist bias -> proj
// All GEMMs as C = A * B^T with bf16 MFMA 16x16x32, f32 accumulate.

typedef __attribute__((ext_vector_type(8))) short bf16x8;
typedef __attribute__((ext_vector_type(4))) float f32x4;
typedef __attribute__((ext_vector_type(4))) unsigned short us4;
typedef __attribute__((ext_vector_type(2))) unsigned int u32x2;

#define MFMA(a, b, c) __builtin_amdgcn_mfma_f32_16x16x32_bf16((a), (b), (c), 0, 0, 0)

__device__ __forceinline__ unsigned short f2bf(float f) {
  unsigned u = __float_as_uint(f);
  u += 0x7fffu + ((u >> 16) & 1u);       // round-to-nearest-even
  return (unsigned short)(u >> 16);
}

__device__ __forceinline__ unsigned cvtpk_bf16(float lo, float hi) {
  unsigned r;
  asm("v_cvt_pk_bf16_f32 %0, %1, %2" : "=v"(r) : "v"(lo), "v"(hi));
  return r;  // lo in bits[15:0], hi in bits[31:16]
}

// ---------- elementwise f32 -> bf16, 8 elems/thread ----------
__global__ __launch_bounds__(256) void k_conv(const float* __restrict__ in,
                                              short* __restrict__ out, int n8) {
  int i = blockIdx.x * blockDim.x + threadIdx.x;
  if (i >= n8) return;
  float4 a = ((const float4*)in)[2 * i];
  float4 b = ((const float4*)in)[2 * i + 1];
  us4 lo, hi;
  lo.x = f2bf(a.x); lo.y = f2bf(a.y); lo.z = f2bf(a.z); lo.w = f2bf(a.w);
  hi.x = f2bf(b.x); hi.y = f2bf(b.y); hi.z = f2bf(b.z); hi.w = f2bf(b.w);
  us4* o = (us4*)(out + 8 * (size_t)i);
  o[0] = lo; o[1] = hi;
}

// ---------- tiled transpose + convert: in[R][C] f32 -> out[C][R] bf16 ----------
__global__ void k_transpose(const float* __restrict__ in, short* __restrict__ out,
                            int R, int C) {
  __shared__ float t[32][33];
  int c0 = blockIdx.x * 32, r0 = blockIdx.y * 32;
  int tx = threadIdx.x, ty = threadIdx.y;
#pragma unroll
  for (int j = 0; j < 32; j += 8)
    t[ty + j][tx] = in[(size_t)(r0 + ty + j) * C + c0 + tx];
  __syncthreads();
#pragma unroll
  for (int j = 0; j < 32; j += 8)
    out[(size_t)(c0 + ty + j) * R + r0 + tx] = (short)f2bf(t[tx][ty + j]);
}

// ---------- GEMM C[M][N] = A[M][K] * (B[N][K])^T, bf16 in, f32 acc ----------
// MODE 0: epilogue scatters qkv columns into Q[bh][n][d], K[bh][n][d], Vt[bh][d][n] (+bias)
// MODE 1: epilogue stores f32 C (+bias) row-major
template <int MODE>
__global__ __launch_bounds__(256) void k_gemm(const short* __restrict__ A,
                                              const short* __restrict__ B,
                                              const float* __restrict__ bias,
                                              void* __restrict__ C0, void* __restrict__ C1,
                                              void* __restrict__ C2, int M, int N, int K) {
  __shared__ __align__(16) short bufA[2][128 * 32];
  __shared__ __align__(16) short bufB[2][128 * 32];
  const int tid = threadIdx.x, lane = tid & 63, wave = tid >> 6;
  const int m0 = blockIdx.y * 128, n0 = blockIdx.x * 128;
  const int wm = (wave >> 1) * 64, wn = (wave & 1) * 64;
  const int KT = K >> 5;
  f32x4 acc[4][4] = {};

  const short* ga = A + (size_t)m0 * K;
  const short* gb = B + (size_t)n0 * K;

#define STAGE(kt, bsel)                                                                   \
  {                                                                                       \
    const short* pa = ga + (kt) * 32;                                                     \
    const short* pb = gb + (kt) * 32;                                                     \
    _Pragma("unroll") for (int i = 0; i < 2; i++) {                                       \
      int s = i * 256 + tid;                                                              \
      __builtin_amdgcn_global_load_lds(                                                   \
          (const __attribute__((address_space(1))) void*)(pa + (size_t)(s >> 2) * K +     \
                                                          (s & 3) * 8),                   \
          (__attribute__((address_space(3))) void*)(&bufA[bsel][(i * 256 + wave * 64) * 8]), \
          16, 0, 0);                                                                      \
      __builtin_amdgcn_global_load_lds(                                                   \
          (const __attribute__((address_space(1))) void*)(pb + (size_t)(s >> 2) * K +     \
                                                          (s & 3) * 8),                   \
          (__attribute__((address_space(3))) void*)(&bufB[bsel][(i * 256 + wave * 64) * 8]), \
          16, 0, 0);                                                                      \
    }                                                                                     \
  }

  STAGE(0, 0)
  for (int kt = 0; kt < KT; ++kt) {
    const int cur = kt & 1;
    __syncthreads();
    if (kt + 1 < KT) STAGE(kt + 1, cur ^ 1)
    bf16x8 af[4], bfr[4];
#pragma unroll
    for (int i = 0; i < 4; i++)
      af[i] = *(const bf16x8*)&bufA[cur][(wm + i * 16 + (lane & 15)) * 32 + (lane >> 4) * 8];
#pragma unroll
    for (int i = 0; i < 4; i++)
      bfr[i] = *(const bf16x8*)&bufB[cur][(wn + i * 16 + (lane & 15)) * 32 + (lane >> 4) * 8];
#pragma unroll
    for (int mi = 0; mi < 4; mi++)
#pragma unroll
      for (int ni = 0; ni < 4; ni++) acc[mi][ni] = MFMA(af[mi], bfr[ni], acc[mi][ni]);
  }
#undef STAGE

#pragma unroll
  for (int mi = 0; mi < 4; mi++)
#pragma unroll
    for (int ni = 0; ni < 4; ni++) {
      int row0 = m0 + wm + mi * 16 + (lane >> 4) * 4;
      int col = n0 + wn + ni * 16 + (lane & 15);
      float bv = bias[col];
      if constexpr (MODE == 0) {
        int which = col >> 10, h = (col >> 6) & 15, d = col & 63;
        int b = row0 >> 11, nt0 = row0 & 2047;
        if (which == 2) {
          us4 pk;
          pk.x = f2bf(acc[mi][ni][0] + bv);
          pk.y = f2bf(acc[mi][ni][1] + bv);
          pk.z = f2bf(acc[mi][ni][2] + bv);
          pk.w = f2bf(acc[mi][ni][3] + bv);
          *(us4*)((short*)C2 + ((size_t)((b << 4) + h) * 64 + d) * 2048 + nt0) = pk;
        } else {
          short* dst = (which == 0) ? (short*)C0 : (short*)C1;
#pragma unroll
          for (int r = 0; r < 4; r++)
            dst[((size_t)((b << 4) + h) * 2048 + nt0 + r) * 64 + d] =
                (short)f2bf(acc[mi][ni][r] + bv);
        }
      } else {
        float* o = (float*)C0;
#pragma unroll
        for (int r = 0; r < 4; r++) o[(size_t)(row0 + r) * N + col] = acc[mi][ni][r] + bv;
      }
    }
}

// ---------- fused attention, swapped-QK layout ----------
// Q[bh][n][d], K[bh][n][d], Vt[bh][d][n] bf16; out attn[b*2048+n][h*64+d] bf16
// QK^T computed as mfma(K, Q): lane owns ONE q-row (lane&15) for the softmax;
// its 16 scores per 64-KV tile sit at k = j*16 + g*4 + r (g = lane>>4).
__global__ __launch_bounds__(256, 4) void k_attn(const short* __restrict__ Qb,
                                                 const short* __restrict__ Kb,
                                                 const short* __restrict__ Vt,
                                                 const float* __restrict__ gamma,
                                                 const float* __restrict__ dist,
                                                 short* __restrict__ attn_out) {
  __shared__ __align__(16) short Plds[4][16][72];
  const int lane = threadIdx.x & 63, wave = threadIdx.x >> 6;
  const int q16 = lane & 15, g = lane >> 4;
  const int bh = blockIdx.y;
  const int qbase = blockIdx.x * 64 + wave * 16;
  const float LOG2E = 1.4426950408889634f;
  const float G2 = gamma[bh] * LOG2E;      // bias slope in log2 domain
  const float SC2 = 0.03125f * LOG2E;      // 1024^-0.5 * log2(e)
  const size_t head = (size_t)bh * 2048 * 64;
  const int qrow = qbase + q16;            // softmax-owner row of this lane
  const float* drow = dist + (size_t)qrow * 2048;

  bf16x8 bq[2];
#pragma unroll
  for (int k0 = 0; k0 < 2; k0++)
    bq[k0] = *(const bf16x8*)&Qb[head + (size_t)qrow * 64 + k0 * 32 + g * 8];

  float m = -3.0e38f, l = 0.f;
  f32x4 acc[4] = {};

  // dist prefetch for kb=0
  float4 ddc[4];
#pragma unroll
  for (int j = 0; j < 4; j++) ddc[j] = *(const float4*)&drow[j * 16 + g * 4];

  for (int kb = 0; kb < 2048; kb += 64) {
    // ---- QK^T (A = K rows, B = Q rows) ----
    f32x4 s[4];
#pragma unroll
    for (int j = 0; j < 4; j++) {
      bf16x8 ak0 = *(const bf16x8*)&Kb[head + (size_t)(kb + j * 16 + q16) * 64 + g * 8];
      bf16x8 ak1 = *(const bf16x8*)&Kb[head + (size_t)(kb + j * 16 + q16) * 64 + 32 + g * 8];
      f32x4 z = {};
      z = MFMA(ak0, bq[0], z);
      s[j] = MFMA(ak1, bq[1], z);
    }
    // ---- issue V loads early (consumed after softmax) ----
    bf16x8 bv[2][4];
#pragma unroll
    for (int k0 = 0; k0 < 2; k0++)
#pragma unroll
      for (int dj = 0; dj < 4; dj++)
        bv[k0][dj] = *(const bf16x8*)&Vt[head + (size_t)(dj * 16 + q16) * 2048 + kb +
                                         k0 * 32 + g * 8];
    // ---- prefetch next iteration's dist tile (wrap on last iter; unused) ----
    const int kbn = (kb + 64) & 2047;
    float4 ddn[4];
#pragma unroll
    for (int j = 0; j < 4; j++) ddn[j] = *(const float4*)&drow[kbn + j * 16 + g * 4];

    // ---- scores in log2 domain: x = s*scale*log2e - gamma*log2e*dist ----
    float x[4][4];
#pragma unroll
    for (int j = 0; j < 4; j++)
#pragma unroll
      for (int r = 0; r < 4; r++) x[j][r] = s[j][r] * SC2 - G2 * ddc[j][r];

    // row max: in-lane over 16, then across the 4 lane-groups sharing this q-row
    float mj[4];
#pragma unroll
    for (int j = 0; j < 4; j++)
      mj[j] = fmaxf(fmaxf(x[j][0], x[j][1]), fmaxf(x[j][2], x[j][3]));
    float mx = fmaxf(fmaxf(mj[0], mj[1]), fmaxf(mj[2], mj[3]));
    mx = fmaxf(mx, __shfl_xor(mx, 16, 64));
    mx = fmaxf(mx, __shfl_xor(mx, 32, 64));
    float mnew = fmaxf(m, mx);

    float p[4][4], ps = 0.f;
#pragma unroll
    for (int j = 0; j < 4; j++)
#pragma unroll
      for (int r = 0; r < 4; r++) {
        p[j][r] = __builtin_amdgcn_exp2f(x[j][r] - mnew);
        ps += p[j][r];
      }
    ps += __shfl_xor(ps, 16, 64);
    ps += __shfl_xor(ps, 32, 64);

    // rescale accumulator only if the running max actually grew (exact skip)
    if (!__all(mx <= m)) {
      float alpha = __builtin_amdgcn_exp2f(m - mnew);
      l *= alpha;
#pragma unroll
      for (int r = 0; r < 4; r++) {
        float ar = __shfl(alpha, (g << 2) | r, 16);
#pragma unroll
        for (int dj = 0; dj < 4; dj++) acc[dj][r] *= ar;
      }
    }
    l += ps;
    m = mnew;

    // ---- P -> LDS (packed bf16, 4x ds_write_b64), then A-frags (2x ds_read_b128) ----
#pragma unroll
    for (int j = 0; j < 4; j++) {
      u32x2 w;
      w.x = cvtpk_bf16(p[j][0], p[j][1]);
      w.y = cvtpk_bf16(p[j][2], p[j][3]);
      *(u32x2*)&Plds[wave][q16][j * 16 + g * 4] = w;
    }
#pragma unroll
    for (int k0 = 0; k0 < 2; k0++) {
      bf16x8 pa = *(const bf16x8*)&Plds[wave][q16][k0 * 32 + g * 8];
#pragma unroll
      for (int dj = 0; dj < 4; dj++) acc[dj] = MFMA(pa, bv[k0][dj], acc[dj]);
    }
#pragma unroll
    for (int j = 0; j < 4; j++) ddc[j] = ddn[j];
  }

  // ---- epilogue: normalize and store ----
  const int b = bh >> 4, h = bh & 15;
  float linv = 1.0f / l;
#pragma unroll
  for (int r = 0; r < 4; r++) {
    float il = __shfl(linv, (g << 2) | r, 16);
    int qr = qbase + g * 4 + r;
    size_t base = ((size_t)b * 2048 + qr) * 1024 + h * 64;
#pragma unroll
    for (int dj = 0; dj < 4; dj++)
      attn_out[base + dj * 16 + q16] = (short)f2bf(acc[dj][r] * il);
  }
}

extern "C" void kernel_launch(void* const* d_in, const int* in_sizes, int n_in,
                              void* d_out, int out_size, void* d_ws, size_t ws_size,
                              hipStream_t stream) {
  const float* x = (const float*)d_in[0];       // [2,2048,1024]
  const float* gamma = (const float*)d_in[1];   // [2,16]
  const float* dist = (const float*)d_in[2];    // [2048,2048]
  const float* qkv_w = (const float*)d_in[3];   // [1024,3072]
  const float* qkv_b = (const float*)d_in[4];   // [3072]
  const float* proj_w = (const float*)d_in[5];  // [1024,1024]
  const float* proj_b = (const float*)d_in[6];  // [1024]
  float* out = (float*)d_out;                   // [4096,1024]

  const size_t MB = 1024 * 1024;
  char* ws = (char*)d_ws;
  short* xb = (short*)(ws + 0 * MB);     // 8MB  x bf16 [4096][1024]
  short* wT = (short*)(ws + 8 * MB);     // 6MB  qkv_w^T bf16 [3072][1024]
  short* pT = (short*)(ws + 14 * MB);    // 2MB  proj_w^T bf16 [1024][1024]
  short* Qb = (short*)(ws + 16 * MB);    // 8MB  [32][2048][64]
  short* Kb = (short*)(ws + 24 * MB);    // 8MB
  short* Vt = (short*)(ws + 32 * MB);    // 8MB  [32][64][2048]
  short* attn = (short*)(ws + 0 * MB);   // reuse xb region: [4096][1024] bf16

  // x -> bf16
  k_conv<<<dim3((4096 * 1024 / 8 + 255) / 256), dim3(256), 0, stream>>>(x, xb, 4096 * 1024 / 8);
  // weight transposes
  k_transpose<<<dim3(96, 32), dim3(32, 8), 0, stream>>>(qkv_w, wT, 1024, 3072);
  k_transpose<<<dim3(32, 32), dim3(32, 8), 0, stream>>>(proj_w, pT, 1024, 1024);
  // qkv projection + scatter
  k_gemm<0><<<dim3(24, 32), dim3(256), 0, stream>>>(xb, wT, qkv_b, Qb, Kb, Vt, 4096, 3072, 1024);
  // attention
  k_attn<<<dim3(32, 32), dim3(256), 0, stream>>>(Qb, Kb, Vt, gamma, dist, attn);
  // output projection
  k_gemm<1><<<dim3(8, 32), dim3(256), 0, stream>>>(attn, pT, proj_b, out, nullptr, nullptr,
                                                   4096, 1024, 1024);
}

// Round 3
// 176.370 us; speedup vs baseline: 2.1665x; 2.0381x over previous
//
#include <hip/hip_runtime.h>
#include <hip/hip_bf16.h>

// ZoomAttention: x[2,2048,1024] -> qkv proj -> 16-head attn with -gamma*dist bias -> proj
// All GEMMs as C = A * B^T with bf16 MFMA 16x16x32, f32 accumulate.

typedef __attribute__((ext_vector_type(8))) short bf16x8;
typedef __attribute__((ext_vector_type(4))) float f32x4;
typedef __attribute__((ext_vector_type(4))) unsigned short us4;
typedef __attribute__((ext_vector_type(2))) unsigned int u32x2;
typedef __attribute__((ext_vector_type(4))) _Float16 f16x4;
typedef __attribute__((ext_vector_type(8))) _Float16 f16x8;

#define MFMA(a, b, c) __builtin_amdgcn_mfma_f32_16x16x32_bf16((a), (b), (c), 0, 0, 0)

__device__ __forceinline__ unsigned short f2bf(float f) {
  unsigned u = __float_as_uint(f);
  u += 0x7fffu + ((u >> 16) & 1u);       // round-to-nearest-even
  return (unsigned short)(u >> 16);
}

__device__ __forceinline__ unsigned cvtpk_bf16(float lo, float hi) {
  unsigned r;
  asm("v_cvt_pk_bf16_f32 %0, %1, %2" : "=v"(r) : "v"(lo), "v"(hi));
  return r;  // lo in bits[15:0], hi in bits[31:16]
}

// ---------- elementwise f32 -> bf16, 8 elems/thread ----------
__global__ __launch_bounds__(256) void k_conv(const float* __restrict__ in,
                                              short* __restrict__ out, int n8) {
  int i = blockIdx.x * blockDim.x + threadIdx.x;
  if (i >= n8) return;
  float4 a = ((const float4*)in)[2 * i];
  float4 b = ((const float4*)in)[2 * i + 1];
  us4 lo, hi;
  lo.x = f2bf(a.x); lo.y = f2bf(a.y); lo.z = f2bf(a.z); lo.w = f2bf(a.w);
  hi.x = f2bf(b.x); hi.y = f2bf(b.y); hi.z = f2bf(b.z); hi.w = f2bf(b.w);
  us4* o = (us4*)(out + 8 * (size_t)i);
  o[0] = lo; o[1] = hi;
}

// ---------- elementwise f32 -> fp16, 8 elems/thread ----------
__global__ __launch_bounds__(256) void k_convh(const float* __restrict__ in,
                                               _Float16* __restrict__ out, int n8) {
  int i = blockIdx.x * blockDim.x + threadIdx.x;
  if (i >= n8) return;
  float4 a = ((const float4*)in)[2 * i];
  float4 b = ((const float4*)in)[2 * i + 1];
  f16x8 v;
  v[0] = (_Float16)a.x; v[1] = (_Float16)a.y; v[2] = (_Float16)a.z; v[3] = (_Float16)a.w;
  v[4] = (_Float16)b.x; v[5] = (_Float16)b.y; v[6] = (_Float16)b.z; v[7] = (_Float16)b.w;
  *(f16x8*)(out + 8 * (size_t)i) = v;
}

// ---------- tiled transpose + convert: in[R][C] f32 -> out[C][R] bf16 ----------
__global__ void k_transpose(const float* __restrict__ in, short* __restrict__ out,
                            int R, int C) {
  __shared__ float t[32][33];
  int c0 = blockIdx.x * 32, r0 = blockIdx.y * 32;
  int tx = threadIdx.x, ty = threadIdx.y;
#pragma unroll
  for (int j = 0; j < 32; j += 8)
    t[ty + j][tx] = in[(size_t)(r0 + ty + j) * C + c0 + tx];
  __syncthreads();
#pragma unroll
  for (int j = 0; j < 32; j += 8)
    out[(size_t)(c0 + ty + j) * R + r0 + tx] = (short)f2bf(t[tx][ty + j]);
}

// ---------- GEMM C[M][N] = A[M][K] * (B[N][K])^T, bf16 in, f32 acc ----------
// MODE 0: epilogue scatters qkv columns into Q[bh][n][d], K[bh][n][d], Vt[bh][d][n] (+bias)
// MODE 1: epilogue stores f32 C (+bias) row-major
template <int MODE>
__global__ __launch_bounds__(256) void k_gemm(const short* __restrict__ A,
                                              const short* __restrict__ B,
                                              const float* __restrict__ bias,
                                              void* __restrict__ C0, void* __restrict__ C1,
                                              void* __restrict__ C2, int M, int N, int K) {
  __shared__ __align__(16) short bufA[2][128 * 32];
  __shared__ __align__(16) short bufB[2][128 * 32];
  const int tid = threadIdx.x, lane = tid & 63, wave = tid >> 6;
  const int m0 = blockIdx.y * 128, n0 = blockIdx.x * 128;
  const int wm = (wave >> 1) * 64, wn = (wave & 1) * 64;
  const int KT = K >> 5;
  f32x4 acc[4][4] = {};

  const short* ga = A + (size_t)m0 * K;
  const short* gb = B + (size_t)n0 * K;

#define STAGE(kt, bsel)                                                                   \
  {                                                                                       \
    const short* pa = ga + (kt) * 32;                                                     \
    const short* pb = gb + (kt) * 32;                                                     \
    _Pragma("unroll") for (int i = 0; i < 2; i++) {                                       \
      int s = i * 256 + tid;                                                              \
      __builtin_amdgcn_global_load_lds(                                                   \
          (const __attribute__((address_space(1))) void*)(pa + (size_t)(s >> 2) * K +     \
                                                          (s & 3) * 8),                   \
          (__attribute__((address_space(3))) void*)(&bufA[bsel][(i * 256 + wave * 64) * 8]), \
          16, 0, 0);                                                                      \
      __builtin_amdgcn_global_load_lds(                                                   \
          (const __attribute__((address_space(1))) void*)(pb + (size_t)(s >> 2) * K +     \
                                                          (s & 3) * 8),                   \
          (__attribute__((address_space(3))) void*)(&bufB[bsel][(i * 256 + wave * 64) * 8]), \
          16, 0, 0);                                                                      \
    }                                                                                     \
  }

  STAGE(0, 0)
  for (int kt = 0; kt < KT; ++kt) {
    const int cur = kt & 1;
    __syncthreads();
    if (kt + 1 < KT) STAGE(kt + 1, cur ^ 1)
    bf16x8 af[4], bfr[4];
#pragma unroll
    for (int i = 0; i < 4; i++)
      af[i] = *(const bf16x8*)&bufA[cur][(wm + i * 16 + (lane & 15)) * 32 + (lane >> 4) * 8];
#pragma unroll
    for (int i = 0; i < 4; i++)
      bfr[i] = *(const bf16x8*)&bufB[cur][(wn + i * 16 + (lane & 15)) * 32 + (lane >> 4) * 8];
#pragma unroll
    for (int mi = 0; mi < 4; mi++)
#pragma unroll
      for (int ni = 0; ni < 4; ni++) acc[mi][ni] = MFMA(af[mi], bfr[ni], acc[mi][ni]);
  }
#undef STAGE

#pragma unroll
  for (int mi = 0; mi < 4; mi++)
#pragma unroll
    for (int ni = 0; ni < 4; ni++) {
      int row0 = m0 + wm + mi * 16 + (lane >> 4) * 4;
      int col = n0 + wn + ni * 16 + (lane & 15);
      float bv = bias[col];
      if constexpr (MODE == 0) {
        int which = col >> 10, h = (col >> 6) & 15, d = col & 63;
        int b = row0 >> 11, nt0 = row0 & 2047;
        if (which == 2) {
          us4 pk;
          pk.x = f2bf(acc[mi][ni][0] + bv);
          pk.y = f2bf(acc[mi][ni][1] + bv);
          pk.z = f2bf(acc[mi][ni][2] + bv);
          pk.w = f2bf(acc[mi][ni][3] + bv);
          *(us4*)((short*)C2 + ((size_t)((b << 4) + h) * 64 + d) * 2048 + nt0) = pk;
        } else {
          short* dst = (which == 0) ? (short*)C0 : (short*)C1;
#pragma unroll
          for (int r = 0; r < 4; r++)
            dst[((size_t)((b << 4) + h) * 2048 + nt0 + r) * 64 + d] =
                (short)f2bf(acc[mi][ni][r] + bv);
        }
      } else {
        float* o = (float*)C0;
#pragma unroll
        for (int r = 0; r < 4; r++) o[(size_t)(row0 + r) * N + col] = acc[mi][ni][r] + bv;
      }
    }
}

// ---------- fused attention, swapped-QK, LDS-staged K/V ----------
// Q[bh][n][d], K[bh][n][d], Vt[bh][d][n] bf16; dist fp16; out attn bf16
// Block: 512 threads (8 waves), 128 q-rows; K/V 64-KV tiles staged to LDS
// (double-buffered, XOR-swizzled via pre-swizzled global source, rule #21).
__global__ __launch_bounds__(512, 4) void k_attn(const short* __restrict__ Qb,
                                                 const short* __restrict__ Kb,
                                                 const short* __restrict__ Vt,
                                                 const float* __restrict__ gamma,
                                                 const _Float16* __restrict__ dh,
                                                 short* __restrict__ attn_out) {
  __shared__ __align__(16) short bufK[2][64 * 64];
  __shared__ __align__(16) short bufV[2][64 * 64];
  __shared__ __align__(16) short Plds[8][16][72];
  const int tid = threadIdx.x;
  const int lane = tid & 63, wave = tid >> 6;
  const int q16 = lane & 15, g = lane >> 4;
  // XCD-aware mapping: XCD = w&7 owns heads [xcd*4, xcd*4+4)
  const int w = blockIdx.x;
  const int xcd = w & 7, idx = w >> 3;           // idx 0..63
  const int bh = (xcd << 2) | (idx >> 4);        // 4 heads per XCD
  const int qblock = idx & 15;                   // 16 q-blocks of 128 rows
  const int qbase = qblock * 128 + wave * 16;
  const float LOG2E = 1.4426950408889634f;
  const float G2 = gamma[bh] * LOG2E;
  const float SC2 = 0.03125f * LOG2E;            // 1024^-0.5 * log2(e)
  const size_t head = (size_t)bh * 2048 * 64;
  const int qrow = qbase + q16;                  // softmax-owner row of this lane
  const _Float16* drow = dh + (size_t)qrow * 2048;
  const char* kptr = (const char*)(Kb + head);   // [2048][64] bf16, 128B rows
  const char* vptr = (const char*)(Vt + head);   // [64][2048] bf16, 4096B rows

  bf16x8 bq[2];
#pragma unroll
  for (int k0 = 0; k0 < 2; k0++)
    bq[k0] = *(const bf16x8*)&Qb[head + (size_t)qrow * 64 + k0 * 32 + g * 8];

  // Stage a 64x64 bf16 tile (8KB): 512 threads x 16B, one issue each.
  // LDS is linear; global source pre-applies the st-XOR (byte ^= (row&7)<<4).
#define STAGEKV(kb, bsel)                                                                  \
  {                                                                                        \
    int o = tid * 16;                                                                      \
    int row = o >> 7, cb = o & 127;                                                        \
    int sw = cb ^ ((row & 7) << 4);                                                        \
    __builtin_amdgcn_global_load_lds(                                                      \
        (const __attribute__((address_space(1))) void*)(kptr + (size_t)(kb) * 128 +       \
                                                        row * 128 + sw),                  \
        (__attribute__((address_space(3))) void*)(&bufK[bsel][wave * 512]), 16, 0, 0);     \
    __builtin_amdgcn_global_load_lds(                                                      \
        (const __attribute__((address_space(1))) void*)(vptr + (size_t)row * 4096 +       \
                                                        (size_t)(kb) * 2 + sw),           \
        (__attribute__((address_space(3))) void*)(&bufV[bsel][wave * 512]), 16, 0, 0);     \
  }

  float m = -3.0e38f, l = 0.f;
  f32x4 acc[4] = {};

  STAGEKV(0, 0)

  // dist prefetch for kb=0 (fp16, 4 consecutive cols per lane)
  f16x4 ddc[4];
#pragma unroll
  for (int j = 0; j < 4; j++) ddc[j] = *(const f16x4*)&drow[j * 16 + g * 4];

  const int swz = (q16 & 7) << 4;

  for (int it = 0; it < 32; ++it) {
    const int cur = it & 1;
    const int kb = it * 64;
    __syncthreads();  // drains vmcnt -> staged tile [cur] ready; guards buf reuse
    if (it + 1 < 32) STAGEKV(kb + 64, cur ^ 1)

    // ---- prefetch next iteration's dist tile ----
    const int kbn = (kb + 64) & 2047;
    f16x4 ddn[4];
#pragma unroll
    for (int j = 0; j < 4; j++) ddn[j] = *(const f16x4*)&drow[kbn + j * 16 + g * 4];

    // ---- QK^T from LDS (A = K rows, B = Q rows) ----
    const char* kbase = (const char*)&bufK[cur][0];
    f32x4 s[4];
#pragma unroll
    for (int j = 0; j < 4; j++) {
      int tr = j * 16 + q16;
      bf16x8 ak0 = *(const bf16x8*)(kbase + tr * 128 + ((g * 16) ^ swz));
      bf16x8 ak1 = *(const bf16x8*)(kbase + tr * 128 + ((64 + g * 16) ^ swz));
      f32x4 z = {};
      z = MFMA(ak0, bq[0], z);
      s[j] = MFMA(ak1, bq[1], z);
    }

    // ---- scores in log2 domain ----
    float x[4][4];
#pragma unroll
    for (int j = 0; j < 4; j++)
#pragma unroll
      for (int r = 0; r < 4; r++) x[j][r] = s[j][r] * SC2 - G2 * (float)ddc[j][r];

    float mj[4];
#pragma unroll
    for (int j = 0; j < 4; j++)
      mj[j] = fmaxf(fmaxf(x[j][0], x[j][1]), fmaxf(x[j][2], x[j][3]));
    float mx = fmaxf(fmaxf(mj[0], mj[1]), fmaxf(mj[2], mj[3]));
    mx = fmaxf(mx, __shfl_xor(mx, 16, 64));
    mx = fmaxf(mx, __shfl_xor(mx, 32, 64));
    float mnew = fmaxf(m, mx);

    float p[4][4], ps = 0.f;
#pragma unroll
    for (int j = 0; j < 4; j++)
#pragma unroll
      for (int r = 0; r < 4; r++) {
        p[j][r] = __builtin_amdgcn_exp2f(x[j][r] - mnew);
        ps += p[j][r];
      }
    ps += __shfl_xor(ps, 16, 64);
    ps += __shfl_xor(ps, 32, 64);

    if (!__all(mx <= m)) {
      float alpha = __builtin_amdgcn_exp2f(m - mnew);
      l *= alpha;
#pragma unroll
      for (int r = 0; r < 4; r++) {
        float ar = __shfl(alpha, (g << 2) | r, 16);
#pragma unroll
        for (int dj = 0; dj < 4; dj++) acc[dj][r] *= ar;
      }
    }
    l += ps;
    m = mnew;

    // ---- P -> LDS (packed bf16), A-frags back, PV from LDS V ----
#pragma unroll
    for (int j = 0; j < 4; j++) {
      u32x2 wv;
      wv.x = cvtpk_bf16(p[j][0], p[j][1]);
      wv.y = cvtpk_bf16(p[j][2], p[j][3]);
      *(u32x2*)&Plds[wave][q16][j * 16 + g * 4] = wv;
    }
    const char* vbase = (const char*)&bufV[cur][0];
#pragma unroll
    for (int k0 = 0; k0 < 2; k0++) {
      bf16x8 pa = *(const bf16x8*)&Plds[wave][q16][k0 * 32 + g * 8];
#pragma unroll
      for (int dj = 0; dj < 4; dj++) {
        int tr = dj * 16 + q16;
        bf16x8 bv = *(const bf16x8*)(vbase + tr * 128 + ((k0 * 64 + g * 16) ^ swz));
        acc[dj] = MFMA(pa, bv, acc[dj]);
      }
    }
#pragma unroll
    for (int j = 0; j < 4; j++) ddc[j] = ddn[j];
  }
#undef STAGEKV

  // ---- epilogue: normalize and store ----
  const int b = bh >> 4, h = bh & 15;
  float linv = 1.0f / l;
#pragma unroll
  for (int r = 0; r < 4; r++) {
    float il = __shfl(linv, (g << 2) | r, 16);
    int qr = qbase + g * 4 + r;
    size_t base = ((size_t)b * 2048 + qr) * 1024 + h * 64;
#pragma unroll
    for (int dj = 0; dj < 4; dj++)
      attn_out[base + dj * 16 + q16] = (short)f2bf(acc[dj][r] * il);
  }
}

extern "C" void kernel_launch(void* const* d_in, const int* in_sizes, int n_in,
                              void* d_out, int out_size, void* d_ws, size_t ws_size,
                              hipStream_t stream) {
  const float* x = (const float*)d_in[0];       // [2,2048,1024]
  const float* gamma = (const float*)d_in[1];   // [2,16]
  const float* dist = (const float*)d_in[2];    // [2048,2048]
  const float* qkv_w = (const float*)d_in[3];   // [1024,3072]
  const float* qkv_b = (const float*)d_in[4];   // [3072]
  const float* proj_w = (const float*)d_in[5];  // [1024,1024]
  const float* proj_b = (const float*)d_in[6];  // [1024]
  float* out = (float*)d_out;                   // [4096,1024]

  const size_t MB = 1024 * 1024;
  char* ws = (char*)d_ws;
  short* xb = (short*)(ws + 0 * MB);     // 8MB  x bf16 [4096][1024]
  short* wT = (short*)(ws + 8 * MB);     // 6MB  qkv_w^T bf16 [3072][1024]
  short* pT = (short*)(ws + 14 * MB);    // 2MB  proj_w^T bf16 [1024][1024]
  short* Qb = (short*)(ws + 16 * MB);    // 8MB  [32][2048][64]
  short* Kb = (short*)(ws + 24 * MB);    // 8MB
  short* Vt = (short*)(ws + 32 * MB);    // 8MB  [32][64][2048]
  _Float16* dhh = (_Float16*)(ws + 40 * MB);  // 8MB dist fp16 [2048][2048]
  short* attn = (short*)(ws + 0 * MB);   // reuse xb region: [4096][1024] bf16

  // x -> bf16; dist -> fp16
  k_conv<<<dim3((4096 * 1024 / 8 + 255) / 256), dim3(256), 0, stream>>>(x, xb, 4096 * 1024 / 8);
  k_convh<<<dim3(2048), dim3(256), 0, stream>>>(dist, dhh, 2048 * 2048 / 8);
  // weight transposes
  k_transpose<<<dim3(96, 32), dim3(32, 8), 0, stream>>>(qkv_w, wT, 1024, 3072);
  k_transpose<<<dim3(32, 32), dim3(32, 8), 0, stream>>>(proj_w, pT, 1024, 1024);
  // qkv projection + scatter
  k_gemm<0><<<dim3(24, 32), dim3(256), 0, stream>>>(xb, wT, qkv_b, Qb, Kb, Vt, 4096, 3072, 1024);
  // attention
  k_attn<<<dim3(512), dim3(512), 0, stream>>>(Qb, Kb, Vt, gamma, dhh, attn);
  // output projection
  k_gemm<1><<<dim3(8, 32), dim3(256), 0, stream>>>(attn, pT, proj_b, out, nullptr, nullptr,
                                                   4096, 1024, 1024);
}